// Round 1
// baseline (130.927 us; speedup 1.0000x reference)
//
#include <hip/hip_runtime.h>
#include <hip/hip_bf16.h>

// Dims fixed by setup_inputs(): b=8, t=64, s=512, qu=vu=d=512.
#define B_  8
#define T_  64
#define S_  512
#define D_  512

#define QN (512 * 512)      // qproj elements (B*T x D)
#define KN (4096 * 512)     // kT elements (B x D x S)

#define TLOG2E 2.8853900817779268f   // 2*log2(e)
#define LOG2E  1.4426950408889634f

typedef __attribute__((ext_vector_type(8))) short bf16x8;
typedef __attribute__((ext_vector_type(4))) float f32x4;

// RNE f32x2 -> packed bf16x2 via v_cvt_pk_bf16_f32.
__device__ __forceinline__ unsigned int pk2(float a, float b) {
    float2 f; f.x = a; f.y = b;
    __hip_bfloat162 h = __float22bfloat162_rn(f);
    return *(unsigned int*)&h;
}
// packed bf16x2 -> two f32 (bit-shift, exact)
#define BF2X(U) __uint_as_float((U) << 16)
#define BF2Y(U) __uint_as_float((U) & 0xffff0000u)

// ---------------------------------------------------------------------------
// bf16 MFMA projection GEMM (R10 576x256 BK=64 dbuf shape — best measured).
// UNCHANGED this round (R13): gemm ~10-15 us, previous changes all neutral.
//   blocks [0,512):   kT = (value @ W2)^T, bf16
//   blocks [512,576): qproj = query @ W1 row-major, f32
// Epilogue: *TLOG2E; q adds (b1+b2) first.
// ---------------------------------------------------------------------------
__global__ __launch_bounds__(256) void mfma_gemm(
    const float* __restrict__ query, const float* __restrict__ value,
    const float* __restrict__ W1, const float* __restrict__ W2,
    const float* __restrict__ b1, const float* __restrict__ b2,
    float* __restrict__ qproj, unsigned short* __restrict__ kTb)
{
    __shared__ __align__(16) unsigned short Ab[2][64][72];
    __shared__ __align__(16) unsigned short Bs[2][64][72];

    const int x = blockIdx.x;
    const float *A, *W;
    int tm, tn;
    bool isq;
    if (x < 512) {
        tm = (x & 7) * 8 + ((x >> 3) & 7);
        tn = x >> 6;
        A = value; W = W2; isq = false;
    } else {
        int r = x - 512;
        tm = r >> 3; tn = r & 7;
        A = query; W = W1; isq = true;
    }

    const int tid  = threadIdx.x;
    const int lane = tid & 63;
    const int wid  = tid >> 6;
    const int wm = (wid & 1) * 32, wn = (wid >> 1) * 32;
    const int fm = lane & 15, fq = lane >> 4;

    f32x4 acc00 = {0.f, 0.f, 0.f, 0.f};
    f32x4 acc01 = acc00, acc10 = acc00, acc11 = acc00;

    const int ar = tid >> 2;
    const int kc = (tid & 3) * 16;
    const float* Ag = A + (size_t)(tm * 64 + ar) * 512 + kc;
    const int c0 = (tid & 15) * 4;
    const int kp = (tid >> 4) * 2;
    const float* Wg = W + (size_t)kp * 512 + tn * 64 + c0;

    float4 av0, av1, av2, av3;
    float4 wv0, wv1, wv2, wv3;

#define LOADT(KOFF) do {                                                      \
        av0 = *(const float4*)(Ag + (KOFF));                                  \
        av1 = *(const float4*)(Ag + (KOFF) + 4);                              \
        av2 = *(const float4*)(Ag + (KOFF) + 8);                              \
        av3 = *(const float4*)(Ag + (KOFF) + 12);                             \
        wv0 = *(const float4*)(Wg + (size_t)(KOFF) * 512);                    \
        wv1 = *(const float4*)(Wg + (size_t)(KOFF) * 512 + 512);              \
        wv2 = *(const float4*)(Wg + (size_t)((KOFF) + 32) * 512);             \
        wv3 = *(const float4*)(Wg + (size_t)((KOFF) + 32) * 512 + 512);       \
    } while (0)

#define STAGE(BUF) do {                                                       \
        uint4 p0, p1;                                                         \
        p0.x = pk2(av0.x, av0.y); p0.y = pk2(av0.z, av0.w);                   \
        p0.z = pk2(av1.x, av1.y); p0.w = pk2(av1.z, av1.w);                   \
        p1.x = pk2(av2.x, av2.y); p1.y = pk2(av2.z, av2.w);                   \
        p1.z = pk2(av3.x, av3.y); p1.w = pk2(av3.z, av3.w);                   \
        *(uint4*)&Ab[BUF][ar][kc]     = p0;                                   \
        *(uint4*)&Ab[BUF][ar][kc + 8] = p1;                                   \
        *(unsigned int*)&Bs[BUF][c0 + 0][kp]      = pk2(wv0.x, wv1.x);        \
        *(unsigned int*)&Bs[BUF][c0 + 1][kp]      = pk2(wv0.y, wv1.y);        \
        *(unsigned int*)&Bs[BUF][c0 + 2][kp]      = pk2(wv0.z, wv1.z);        \
        *(unsigned int*)&Bs[BUF][c0 + 3][kp]      = pk2(wv0.w, wv1.w);        \
        *(unsigned int*)&Bs[BUF][c0 + 0][kp + 32] = pk2(wv2.x, wv3.x);        \
        *(unsigned int*)&Bs[BUF][c0 + 1][kp + 32] = pk2(wv2.y, wv3.y);        \
        *(unsigned int*)&Bs[BUF][c0 + 2][kp + 32] = pk2(wv2.z, wv3.z);        \
        *(unsigned int*)&Bs[BUF][c0 + 3][kp + 32] = pk2(wv2.w, wv3.w);        \
    } while (0)

    LOADT(0);
    STAGE(0);
    LOADT(64);
    __syncthreads();

    for (int i = 0; i < 8; ++i) {
        const int cur = i & 1, nxt = cur ^ 1;
        bf16x8 a0, a1, b0, b1v;
#pragma unroll
        for (int kk = 0; kk < 64; kk += 32) {
            a0  = *(const bf16x8*)&Ab[cur][wm + fm][kk + fq * 8];
            a1  = *(const bf16x8*)&Ab[cur][wm + 16 + fm][kk + fq * 8];
            b0  = *(const bf16x8*)&Bs[cur][wn + fm][kk + fq * 8];
            b1v = *(const bf16x8*)&Bs[cur][wn + 16 + fm][kk + fq * 8];
            acc00 = __builtin_amdgcn_mfma_f32_16x16x32_bf16(a0, b0,  acc00, 0, 0, 0);
            acc01 = __builtin_amdgcn_mfma_f32_16x16x32_bf16(a0, b1v, acc01, 0, 0, 0);
            acc10 = __builtin_amdgcn_mfma_f32_16x16x32_bf16(a1, b0,  acc10, 0, 0, 0);
            acc11 = __builtin_amdgcn_mfma_f32_16x16x32_bf16(a1, b1v, acc11, 0, 0, 0);
        }
        if (i < 7) {
            STAGE(nxt);
            const int kn = ((i + 2) & 7) * 64;
            LOADT(kn);
        }
        __syncthreads();
    }
#undef STAGE
#undef LOADT

    // C/D layout (m89-verified): col = lane&15, row = fq*4 + reg.
    const int n0 = tn * 64 + wn + fm;
    const int n1 = n0 + 16;
    const int m0 = tm * 64 + wm + fq * 4;
    if (isq) {
        float bias0 = b1[n0] + b2[n0];
        float bias1 = b1[n1] + b2[n1];
#pragma unroll
        for (int r = 0; r < 4; ++r) {
            qproj[(size_t)(m0 + r) * 512 + n0]      = (acc00[r] + bias0) * TLOG2E;
            qproj[(size_t)(m0 + r) * 512 + n1]      = (acc01[r] + bias1) * TLOG2E;
            qproj[(size_t)(m0 + 16 + r) * 512 + n0] = (acc10[r] + bias0) * TLOG2E;
            qproj[(size_t)(m0 + 16 + r) * 512 + n1] = (acc11[r] + bias1) * TLOG2E;
        }
    } else {
        // kTb[(bb*512 + d)*512 + s] bf16; acc regs = 4 consecutive s at d.
        const int bb = m0 >> 9;
        const int sl = m0 & 511;
        unsigned short* kb = kTb + (size_t)(bb * 512) * 512;
        uint2 o;
        o.x = pk2(acc00[0] * TLOG2E, acc00[1] * TLOG2E);
        o.y = pk2(acc00[2] * TLOG2E, acc00[3] * TLOG2E);
        *(uint2*)(kb + (size_t)n0 * 512 + sl) = o;
        o.x = pk2(acc10[0] * TLOG2E, acc10[1] * TLOG2E);
        o.y = pk2(acc10[2] * TLOG2E, acc10[3] * TLOG2E);
        *(uint2*)(kb + (size_t)n0 * 512 + sl + 16) = o;
        o.x = pk2(acc01[0] * TLOG2E, acc01[1] * TLOG2E);
        o.y = pk2(acc01[2] * TLOG2E, acc01[3] * TLOG2E);
        *(uint2*)(kb + (size_t)n1 * 512 + sl) = o;
        o.x = pk2(acc11[0] * TLOG2E, acc11[1] * TLOG2E);
        o.y = pk2(acc11[2] * TLOG2E, acc11[3] * TLOG2E);
        *(uint2*)(kb + (size_t)n1 * 512 + sl + 16) = o;
    }
}

// ---------------------------------------------------------------------------
// R13: scores + softmax ONLY (phase-3 context moved to ctx_gemm). Phase 3
// previously re-read value[b] (1 MB) per block = 256 MB L2 traffic, 32 MB
// through a single XCD's L2 per b (blk&7==b pins XCD) ~= 7.4 us serialized
// after softmax. Kernel now ends right after writing attn.
// ---------------------------------------------------------------------------
__global__ __launch_bounds__(1024) void fused_attn(
    const float* __restrict__ qproj, const unsigned short* __restrict__ kTb,
    const int*   __restrict__ mask,  const float* __restrict__ scale,
    float* __restrict__ attn)
{
    const int blk = blockIdx.x;
    const int b  = blk & 7;
    const int tp = blk >> 3;          // 0..31
    const size_t row0 = (size_t)(b * T_ + tp * 2);

    __shared__ __align__(16) float q0A[512];
    __shared__ __align__(16) float dA[512];
    __shared__ __align__(16) float cA[512];
    __shared__ __align__(16) float4 pex[4][256];   // (t0s0,t1s0,t0s1,t1s1)
    __shared__ float2 red2[16];

    const int tid  = threadIdx.x;     // 0..1023
    const int lane = tid & 63;
    const int wid  = tid >> 6;        // 0..15

    // ---- Phase 0: q0 / delta / scale into LDS ----
    if (tid < 512) {
        float q0v = qproj[row0 * D_ + tid];
        float q1v = qproj[(row0 + 1) * D_ + tid];
        q0A[tid] = q0v;
        dA[tid]  = __builtin_amdgcn_exp2f(q1v - q0v);   // delta_d
        cA[tid]  = scale[tid];
    }
    __syncthreads();

    // ---- Phase 1: thread (sp, dq), bf16 kT ----
    const int sp  = tid & 255;        // s-pair
    const int dq  = tid >> 8;         // d-quarter
    const int dlo = dq * 128;
    const unsigned short* kb = kTb + ((size_t)(b * 512 + dlo)) * 512 + sp * 2;

    float p00 = 0.f, p10 = 0.f, p01 = 0.f, p11 = 0.f;

    unsigned int nf0 = *(const unsigned int*)(kb);
    unsigned int nf1 = *(const unsigned int*)(kb + 512);
    unsigned int nf2 = *(const unsigned int*)(kb + 1024);
    unsigned int nf3 = *(const unsigned int*)(kb + 1536);

#define SC2(KU, QV, DV, CV) do {                                              \
        float e0 = __builtin_amdgcn_exp2f((QV) + BF2X(KU));                   \
        float ra = __builtin_amdgcn_rcpf(e0 + 1.0f);                          \
        float rb = __builtin_amdgcn_rcpf(fmaf(e0, (DV), 1.0f));               \
        p00 = fmaf((CV), ra, p00); p10 = fmaf((CV), rb, p10);                 \
        float e1 = __builtin_amdgcn_exp2f((QV) + BF2Y(KU));                   \
        float rc = __builtin_amdgcn_rcpf(e1 + 1.0f);                          \
        float rd = __builtin_amdgcn_rcpf(fmaf(e1, (DV), 1.0f));               \
        p01 = fmaf((CV), rc, p01); p11 = fmaf((CV), rd, p11);                 \
    } while (0)

    for (int g = 0; g < 32; ++g) {
        unsigned int kf0 = nf0, kf1 = nf1, kf2 = nf2, kf3 = nf3;
        const unsigned short* nb = kb + (size_t)(((g + 1) & 31) * 4) * 512;
        nf0 = *(const unsigned int*)(nb);
        nf1 = *(const unsigned int*)(nb + 512);
        nf2 = *(const unsigned int*)(nb + 1024);
        nf3 = *(const unsigned int*)(nb + 1536);
        const int d0 = dlo + g * 4;
        float4 q4 = *(const float4*)&q0A[d0];
        float4 dl = *(const float4*)&dA[d0];
        float4 c4 = *(const float4*)&cA[d0];
        SC2(kf0, q4.x, dl.x, c4.x);
        SC2(kf1, q4.y, dl.y, c4.y);
        SC2(kf2, q4.z, dl.z, c4.z);
        SC2(kf3, q4.w, dl.w, c4.w);
    }
#undef SC2

    {
        float4 pq; pq.x = p00; pq.y = p10; pq.z = p01; pq.w = p11;
        pex[dq][sp] = pq;
    }
    __syncthreads();

    // ---- Phase 2: softmax over 512 s (waves 0-7), barriers block-wide ----
    float x0 = 0.f, x1 = 0.f;
    if (tid < 512) {
        const int s = tid;
        const int s2 = s >> 1;
        const bool odd = (s & 1) != 0;
        float4 r0 = pex[0][s2], r1 = pex[1][s2];
        float4 r2 = pex[2][s2], r3 = pex[3][s2];
        float pt0 = odd ? ((r0.z + r1.z) + (r2.z + r3.z))
                        : ((r0.x + r1.x) + (r2.x + r3.x));
        float pt1 = odd ? ((r0.w + r1.w) + (r2.w + r3.w))
                        : ((r0.y + r1.y) + (r2.y + r3.y));
        const int m = mask[b * S_ + s];
        x0 = m ? (-2.0f * pt0) : -1e9f;
        x1 = m ? (-2.0f * pt1) : -1e9f;
        float2 mx; mx.x = x0; mx.y = x1;
#pragma unroll
        for (int off = 32; off >= 1; off >>= 1) {
            mx.x = fmaxf(mx.x, __shfl_xor(mx.x, off));
            mx.y = fmaxf(mx.y, __shfl_xor(mx.y, off));
        }
        if (lane == 0) red2[wid] = mx;
    }
    __syncthreads();

    float e0 = 0.f, e1 = 0.f;
    if (tid < 512) {
        float2 M = red2[0];
#pragma unroll
        for (int i = 1; i < 8; ++i) {
            M.x = fmaxf(M.x, red2[i].x);
            M.y = fmaxf(M.y, red2[i].y);
        }
        e0 = __builtin_amdgcn_exp2f((x0 - M.x) * LOG2E);
        e1 = __builtin_amdgcn_exp2f((x1 - M.y) * LOG2E);
        float2 sm; sm.x = e0; sm.y = e1;
#pragma unroll
        for (int off = 32; off >= 1; off >>= 1) {
            sm.x += __shfl_xor(sm.x, off);
            sm.y += __shfl_xor(sm.y, off);
        }
        if (lane == 0) red2[8 + wid] = sm;
    }
    __syncthreads();

    if (tid < 512) {
        const int s = tid;
        float2 SS = red2[8];
#pragma unroll
        for (int i = 9; i < 16; ++i) {
            SS.x += red2[i].x;
            SS.y += red2[i].y;
        }
        const float w0 = e0 * __builtin_amdgcn_rcpf(SS.x);
        const float w1 = e1 * __builtin_amdgcn_rcpf(SS.y);
        attn[row0 * S_ + s]       = w0;
        attn[(row0 + 1) * S_ + s] = w1;
    }
}

// ---------------------------------------------------------------------------
// R13 NEW: ctx = attn @ value with reuse-friendly partition.
// grid 256 = b(8, low bits -> same XCD as producer) x t-tile(4 of 16t) x
// v-chunk(8 of 64v). Per block: attn tile 16x512 staged once in LDS (padded
// to 516 to break the 4-way t-bank alias), value staged in 64-s strips.
// Global value traffic: 32 MB total (4 MB/XCD) vs 256 MB in the old fused
// phase 3. Compute ~2.3 us VALU, memory ~1 us L2.
// ---------------------------------------------------------------------------
__global__ __launch_bounds__(256) void ctx_gemm(
    const float* __restrict__ attn, const float* __restrict__ value,
    float* __restrict__ ctx)
{
    const int blk = blockIdx.x;
    const int b  = blk & 7;
    const int r  = blk >> 3;          // 0..31
    const int tt = r & 3;             // t-tile index (16 t each)
    const int vc = r >> 2;            // v-chunk index (64 v each)

    __shared__ __align__(16) float wA[16][516];   // +4 pad: t-rows hit distinct banks
    __shared__ __align__(16) float vS[64][64];

    const int tid = threadIdx.x;      // 0..255

    // stage attn tile [16][512]
    const float* ab = attn + (size_t)(b * T_ + tt * 16) * S_;
#pragma unroll
    for (int i = 0; i < 8; ++i) {
        const int f   = i * 256 + tid;        // float4 index over 16*128
        const int row = f >> 7, c4 = f & 127;
        *(float4*)&wA[row][c4 * 4] = *(const float4*)(ab + (size_t)row * S_ + c4 * 4);
    }

    const int t  = tid >> 4;          // 0..15
    const int v4 = tid & 15;          // 0..15
    const float* vb = value + (size_t)(b * S_) * D_ + vc * 64;

    float4 acc; acc.x = 0.f; acc.y = 0.f; acc.z = 0.f; acc.w = 0.f;

    for (int strip = 0; strip < 8; ++strip) {
        __syncthreads();              // strip 0: covers wA staging too
#pragma unroll
        for (int j = 0; j < 4; ++j) {
            const int f  = j * 256 + tid;     // float4 index over 64*16
            const int sr = f >> 4, c4 = f & 15;
            *(float4*)&vS[sr][c4 * 4] =
                *(const float4*)(vb + (size_t)(strip * 64 + sr) * D_ + c4 * 4);
        }
        __syncthreads();
        const float* wrow = &wA[t][strip * 64];
#pragma unroll 4
        for (int s = 0; s < 64; s += 4) {
            float4 w4 = *(const float4*)(wrow + s);
            float4 va = *(const float4*)&vS[s + 0][v4 * 4];
            acc.x = fmaf(w4.x, va.x, acc.x); acc.y = fmaf(w4.x, va.y, acc.y);
            acc.z = fmaf(w4.x, va.z, acc.z); acc.w = fmaf(w4.x, va.w, acc.w);
            float4 vbv = *(const float4*)&vS[s + 1][v4 * 4];
            acc.x = fmaf(w4.y, vbv.x, acc.x); acc.y = fmaf(w4.y, vbv.y, acc.y);
            acc.z = fmaf(w4.y, vbv.z, acc.z); acc.w = fmaf(w4.y, vbv.w, acc.w);
            float4 vcv = *(const float4*)&vS[s + 2][v4 * 4];
            acc.x = fmaf(w4.z, vcv.x, acc.x); acc.y = fmaf(w4.z, vcv.y, acc.y);
            acc.z = fmaf(w4.z, vcv.z, acc.z); acc.w = fmaf(w4.z, vcv.w, acc.w);
            float4 vdv = *(const float4*)&vS[s + 3][v4 * 4];
            acc.x = fmaf(w4.w, vdv.x, acc.x); acc.y = fmaf(w4.w, vdv.y, acc.y);
            acc.z = fmaf(w4.w, vdv.z, acc.z); acc.w = fmaf(w4.w, vdv.w, acc.w);
        }
    }

    *(float4*)(ctx + (size_t)(b * T_ + tt * 16 + t) * D_ + vc * 64 + v4 * 4) = acc;
}

extern "C" void kernel_launch(void* const* d_in, const int* in_sizes, int n_in,
                              void* d_out, int out_size, void* d_ws, size_t ws_size,
                              hipStream_t stream) {
    const float* query = (const float*)d_in[0];
    const float* value = (const float*)d_in[1];
    const int*   mask  = (const int*)  d_in[2];
    const float* W1w   = (const float*)d_in[3];
    const float* W1b   = (const float*)d_in[4];
    const float* W2w   = (const float*)d_in[5];
    const float* W2b   = (const float*)d_in[6];
    const float* scale = (const float*)d_in[7];

    float* ctx  = (float*)d_out;
    float* attn = (float*)d_out + (size_t)B_ * T_ * D_;

    float* qproj = (float*)d_ws;                       // QN f32 (1 MB)
    unsigned short* kTb = (unsigned short*)(qproj + (size_t)QN);  // KN bf16 (4 MB)

    mfma_gemm<<<576, 256, 0, stream>>>(query, value, W1w, W2w, W1b, W2b,
                                       qproj, kTb);
    fused_attn<<<256, 1024, 0, stream>>>(qproj, kTb, mask, scale, attn);
    ctx_gemm<<<256, 256, 0, stream>>>(attn, value, ctx);
}

// Round 2
// 124.137 us; speedup vs baseline: 1.0547x; 1.0547x over previous
//
#include <hip/hip_runtime.h>
#include <hip/hip_bf16.h>
#include <hip/hip_fp16.h>

// Dims fixed by setup_inputs(): b=8, t=64, s=512, qu=vu=d=512.
#define B_  8
#define T_  64
#define S_  512
#define D_  512

#define QN (512 * 512)      // qproj elements (B*T x D)
#define KN (4096 * 512)     // kT elements (B x D x S)

#define TLOG2E 2.8853900817779268f   // 2*log2(e)
#define LOG2E  1.4426950408889634f

typedef __attribute__((ext_vector_type(8))) short bf16x8;
typedef __attribute__((ext_vector_type(4))) float f32x4;

// RNE f32x2 -> packed bf16x2 via v_cvt_pk_bf16_f32.
__device__ __forceinline__ unsigned int pk2(float a, float b) {
    float2 f; f.x = a; f.y = b;
    __hip_bfloat162 h = __float22bfloat162_rn(f);
    return *(unsigned int*)&h;
}
// RNE f32x2 -> packed fp16x2
__device__ __forceinline__ unsigned int pkh(float a, float b) {
    __half2 h = __floats2half2_rn(a, b);
    return *(unsigned int*)&h;
}
// packed fp16x2 -> two f32
__device__ __forceinline__ float2 up2(unsigned int u) {
    __half2 h = *(__half2*)&u;
    return __half22float2(h);
}

// ---------------------------------------------------------------------------
// bf16 MFMA projection GEMM (R10 576x256 BK=64 dbuf shape — best measured).
// R14 change: k-branch epilogue stores E_k = exp2(k*2log2e) as FP16
// (exp factorization: e^{2(q+k)} = e^{2q} * e^{2k}). This removes the exp2
// from the consumer's 134M-element inner loop (trans-pipe floor 10.2us ->
// 6.8us). fp16 E_k (rel err 2^-11) is MORE accurate than bf16 k was.
//   blocks [0,512):   kTb = exp2((value @ W2)^T * TLOG2E), fp16
//   blocks [512,576): qproj = (query @ W1 + b1 + b2) * TLOG2E, f32
// ---------------------------------------------------------------------------
__global__ __launch_bounds__(256) void mfma_gemm(
    const float* __restrict__ query, const float* __restrict__ value,
    const float* __restrict__ W1, const float* __restrict__ W2,
    const float* __restrict__ b1, const float* __restrict__ b2,
    float* __restrict__ qproj, unsigned short* __restrict__ kTb)
{
    __shared__ __align__(16) unsigned short Ab[2][64][72];
    __shared__ __align__(16) unsigned short Bs[2][64][72];

    const int x = blockIdx.x;
    const float *A, *W;
    int tm, tn;
    bool isq;
    if (x < 512) {
        tm = (x & 7) * 8 + ((x >> 3) & 7);
        tn = x >> 6;
        A = value; W = W2; isq = false;
    } else {
        int r = x - 512;
        tm = r >> 3; tn = r & 7;
        A = query; W = W1; isq = true;
    }

    const int tid  = threadIdx.x;
    const int lane = tid & 63;
    const int wid  = tid >> 6;
    const int wm = (wid & 1) * 32, wn = (wid >> 1) * 32;
    const int fm = lane & 15, fq = lane >> 4;

    f32x4 acc00 = {0.f, 0.f, 0.f, 0.f};
    f32x4 acc01 = acc00, acc10 = acc00, acc11 = acc00;

    const int ar = tid >> 2;
    const int kc = (tid & 3) * 16;
    const float* Ag = A + (size_t)(tm * 64 + ar) * 512 + kc;
    const int c0 = (tid & 15) * 4;
    const int kp = (tid >> 4) * 2;
    const float* Wg = W + (size_t)kp * 512 + tn * 64 + c0;

    float4 av0, av1, av2, av3;
    float4 wv0, wv1, wv2, wv3;

#define LOADT(KOFF) do {                                                      \
        av0 = *(const float4*)(Ag + (KOFF));                                  \
        av1 = *(const float4*)(Ag + (KOFF) + 4);                              \
        av2 = *(const float4*)(Ag + (KOFF) + 8);                              \
        av3 = *(const float4*)(Ag + (KOFF) + 12);                             \
        wv0 = *(const float4*)(Wg + (size_t)(KOFF) * 512);                    \
        wv1 = *(const float4*)(Wg + (size_t)(KOFF) * 512 + 512);              \
        wv2 = *(const float4*)(Wg + (size_t)((KOFF) + 32) * 512);             \
        wv3 = *(const float4*)(Wg + (size_t)((KOFF) + 32) * 512 + 512);       \
    } while (0)

#define STAGE(BUF) do {                                                       \
        uint4 p0, p1;                                                         \
        p0.x = pk2(av0.x, av0.y); p0.y = pk2(av0.z, av0.w);                   \
        p0.z = pk2(av1.x, av1.y); p0.w = pk2(av1.z, av1.w);                   \
        p1.x = pk2(av2.x, av2.y); p1.y = pk2(av2.z, av2.w);                   \
        p1.z = pk2(av3.x, av3.y); p1.w = pk2(av3.z, av3.w);                   \
        *(uint4*)&Ab[BUF][ar][kc]     = p0;                                   \
        *(uint4*)&Ab[BUF][ar][kc + 8] = p1;                                   \
        *(unsigned int*)&Bs[BUF][c0 + 0][kp]      = pk2(wv0.x, wv1.x);        \
        *(unsigned int*)&Bs[BUF][c0 + 1][kp]      = pk2(wv0.y, wv1.y);        \
        *(unsigned int*)&Bs[BUF][c0 + 2][kp]      = pk2(wv0.z, wv1.z);        \
        *(unsigned int*)&Bs[BUF][c0 + 3][kp]      = pk2(wv0.w, wv1.w);        \
        *(unsigned int*)&Bs[BUF][c0 + 0][kp + 32] = pk2(wv2.x, wv3.x);        \
        *(unsigned int*)&Bs[BUF][c0 + 1][kp + 32] = pk2(wv2.y, wv3.y);        \
        *(unsigned int*)&Bs[BUF][c0 + 2][kp + 32] = pk2(wv2.z, wv3.z);        \
        *(unsigned int*)&Bs[BUF][c0 + 3][kp + 32] = pk2(wv2.w, wv3.w);        \
    } while (0)

    LOADT(0);
    STAGE(0);
    LOADT(64);
    __syncthreads();

    for (int i = 0; i < 8; ++i) {
        const int cur = i & 1, nxt = cur ^ 1;
        bf16x8 a0, a1, b0, b1v;
#pragma unroll
        for (int kk = 0; kk < 64; kk += 32) {
            a0  = *(const bf16x8*)&Ab[cur][wm + fm][kk + fq * 8];
            a1  = *(const bf16x8*)&Ab[cur][wm + 16 + fm][kk + fq * 8];
            b0  = *(const bf16x8*)&Bs[cur][wn + fm][kk + fq * 8];
            b1v = *(const bf16x8*)&Bs[cur][wn + 16 + fm][kk + fq * 8];
            acc00 = __builtin_amdgcn_mfma_f32_16x16x32_bf16(a0, b0,  acc00, 0, 0, 0);
            acc01 = __builtin_amdgcn_mfma_f32_16x16x32_bf16(a0, b1v, acc01, 0, 0, 0);
            acc10 = __builtin_amdgcn_mfma_f32_16x16x32_bf16(a1, b0,  acc10, 0, 0, 0);
            acc11 = __builtin_amdgcn_mfma_f32_16x16x32_bf16(a1, b1v, acc11, 0, 0, 0);
        }
        if (i < 7) {
            STAGE(nxt);
            const int kn = ((i + 2) & 7) * 64;
            LOADT(kn);
        }
        __syncthreads();
    }
#undef STAGE
#undef LOADT

    // C/D layout (m89-verified): col = lane&15, row = fq*4 + reg.
    const int n0 = tn * 64 + wn + fm;
    const int n1 = n0 + 16;
    const int m0 = tm * 64 + wm + fq * 4;
    if (isq) {
        float bias0 = b1[n0] + b2[n0];
        float bias1 = b1[n1] + b2[n1];
#pragma unroll
        for (int r = 0; r < 4; ++r) {
            qproj[(size_t)(m0 + r) * 512 + n0]      = (acc00[r] + bias0) * TLOG2E;
            qproj[(size_t)(m0 + r) * 512 + n1]      = (acc01[r] + bias1) * TLOG2E;
            qproj[(size_t)(m0 + 16 + r) * 512 + n0] = (acc10[r] + bias0) * TLOG2E;
            qproj[(size_t)(m0 + 16 + r) * 512 + n1] = (acc11[r] + bias1) * TLOG2E;
        }
    } else {
        // kTb[(bb*512 + d)*512 + s] fp16 E_k; acc regs = 4 consecutive s at d.
        const int bb = m0 >> 9;
        const int sl = m0 & 511;
        unsigned short* kb = kTb + (size_t)(bb * 512) * 512;
#define EX2(V) __builtin_amdgcn_exp2f((V) * TLOG2E)
        uint2 o;
        o.x = pkh(EX2(acc00[0]), EX2(acc00[1]));
        o.y = pkh(EX2(acc00[2]), EX2(acc00[3]));
        *(uint2*)(kb + (size_t)n0 * 512 + sl) = o;
        o.x = pkh(EX2(acc10[0]), EX2(acc10[1]));
        o.y = pkh(EX2(acc10[2]), EX2(acc10[3]));
        *(uint2*)(kb + (size_t)n0 * 512 + sl + 16) = o;
        o.x = pkh(EX2(acc01[0]), EX2(acc01[1]));
        o.y = pkh(EX2(acc01[2]), EX2(acc01[3]));
        *(uint2*)(kb + (size_t)n1 * 512 + sl) = o;
        o.x = pkh(EX2(acc11[0]), EX2(acc11[1]));
        o.y = pkh(EX2(acc11[2]), EX2(acc11[3]));
        *(uint2*)(kb + (size_t)n1 * 512 + sl + 16) = o;
#undef EX2
    }
}

// ---------------------------------------------------------------------------
// R14: fused scores + softmax + context (R12 3-phase structure restored —
// the R13 ctx split regressed ~2us: phase 3 overlaps fine across blocks,
// the split just added a launch + attn round-trip).
// Phase 1 change: kTb now holds E_k = e^{2k} (fp16). Inner loop does
// e = Eq * Ek (VALU mul) instead of exp2(q+k) (trans): trans ops per
// (t,s,d) drop 1.5 -> 1.0 (only the rcp remains).
// ---------------------------------------------------------------------------
__global__ __launch_bounds__(1024) void fused_attn(
    const float* __restrict__ qproj, const unsigned short* __restrict__ kTb,
    const int*   __restrict__ mask,  const float* __restrict__ scale,
    const float* __restrict__ value,
    float* __restrict__ ctx, float* __restrict__ attn)
{
    const int blk = blockIdx.x;
    const int b  = blk & 7;
    const int tp = blk >> 3;          // 0..31
    const size_t row0 = (size_t)(b * T_ + tp * 2);

    __shared__ __align__(16) float q0A[512];   // E_q0 = e^{2 q0}
    __shared__ __align__(16) float dA[512];    // delta = e^{2 (q1-q0)}
    __shared__ __align__(16) float cA[512];
    __shared__ __align__(16) float4 pex[4][256];   // (t0s0,t1s0,t0s1,t1s1)
    __shared__ __align__(16) float2 wp2[512];
    __shared__ __align__(16) float4 part[2][8][128];
    __shared__ float2 red2[16];

    const int tid  = threadIdx.x;     // 0..1023
    const int lane = tid & 63;
    const int wid  = tid >> 6;        // 0..15

    // ---- Phase 0: E_q0 / delta / scale into LDS ----
    if (tid < 512) {
        float q0v = qproj[row0 * D_ + tid];          // pre-scaled by 2*log2(e)
        float q1v = qproj[(row0 + 1) * D_ + tid];
        q0A[tid] = __builtin_amdgcn_exp2f(q0v);      // E_q0
        dA[tid]  = __builtin_amdgcn_exp2f(q1v - q0v);
        cA[tid]  = scale[tid];
    }
    __syncthreads();

    // ---- Phase 1: thread (sp, dq), fp16 E_k ----
    const int sp  = tid & 255;        // s-pair
    const int dq  = tid >> 8;         // d-quarter
    const int dlo = dq * 128;
    const unsigned short* kb = kTb + ((size_t)(b * 512 + dlo)) * 512 + sp * 2;

    float p00 = 0.f, p10 = 0.f, p01 = 0.f, p11 = 0.f;

    unsigned int nf0 = *(const unsigned int*)(kb);
    unsigned int nf1 = *(const unsigned int*)(kb + 512);
    unsigned int nf2 = *(const unsigned int*)(kb + 1024);
    unsigned int nf3 = *(const unsigned int*)(kb + 1536);

#define SC2(KU, EQ, DV, CV) do {                                              \
        float2 ek = up2(KU);                                                  \
        float e0 = (EQ) * ek.x;                                               \
        float ra = __builtin_amdgcn_rcpf(e0 + 1.0f);                          \
        float rb = __builtin_amdgcn_rcpf(fmaf(e0, (DV), 1.0f));               \
        p00 = fmaf((CV), ra, p00); p10 = fmaf((CV), rb, p10);                 \
        float e1 = (EQ) * ek.y;                                               \
        float rc = __builtin_amdgcn_rcpf(e1 + 1.0f);                          \
        float rd = __builtin_amdgcn_rcpf(fmaf(e1, (DV), 1.0f));               \
        p01 = fmaf((CV), rc, p01); p11 = fmaf((CV), rd, p11);                 \
    } while (0)

    for (int g = 0; g < 32; ++g) {
        unsigned int kf0 = nf0, kf1 = nf1, kf2 = nf2, kf3 = nf3;
        const unsigned short* nb = kb + (size_t)(((g + 1) & 31) * 4) * 512;
        nf0 = *(const unsigned int*)(nb);
        nf1 = *(const unsigned int*)(nb + 512);
        nf2 = *(const unsigned int*)(nb + 1024);
        nf3 = *(const unsigned int*)(nb + 1536);
        const int d0 = dlo + g * 4;
        float4 q4 = *(const float4*)&q0A[d0];
        float4 dl = *(const float4*)&dA[d0];
        float4 c4 = *(const float4*)&cA[d0];
        SC2(kf0, q4.x, dl.x, c4.x);
        SC2(kf1, q4.y, dl.y, c4.y);
        SC2(kf2, q4.z, dl.z, c4.z);
        SC2(kf3, q4.w, dl.w, c4.w);
    }
#undef SC2

    {
        float4 pq; pq.x = p00; pq.y = p10; pq.z = p01; pq.w = p11;
        pex[dq][sp] = pq;
    }
    __syncthreads();

    // ---- Phase 2: softmax over 512 s (waves 0-7), barriers block-wide ----
    float x0 = 0.f, x1 = 0.f;
    if (tid < 512) {
        const int s = tid;
        const int s2 = s >> 1;
        const bool odd = (s & 1) != 0;
        float4 r0 = pex[0][s2], r1 = pex[1][s2];
        float4 r2 = pex[2][s2], r3 = pex[3][s2];
        float pt0 = odd ? ((r0.z + r1.z) + (r2.z + r3.z))
                        : ((r0.x + r1.x) + (r2.x + r3.x));
        float pt1 = odd ? ((r0.w + r1.w) + (r2.w + r3.w))
                        : ((r0.y + r1.y) + (r2.y + r3.y));
        const int m = mask[b * S_ + s];
        x0 = m ? (-2.0f * pt0) : -1e9f;
        x1 = m ? (-2.0f * pt1) : -1e9f;
        float2 mx; mx.x = x0; mx.y = x1;
#pragma unroll
        for (int off = 32; off >= 1; off >>= 1) {
            mx.x = fmaxf(mx.x, __shfl_xor(mx.x, off));
            mx.y = fmaxf(mx.y, __shfl_xor(mx.y, off));
        }
        if (lane == 0) red2[wid] = mx;
    }
    __syncthreads();

    float e0 = 0.f, e1 = 0.f;
    if (tid < 512) {
        float2 M = red2[0];
#pragma unroll
        for (int i = 1; i < 8; ++i) {
            M.x = fmaxf(M.x, red2[i].x);
            M.y = fmaxf(M.y, red2[i].y);
        }
        e0 = __builtin_amdgcn_exp2f((x0 - M.x) * LOG2E);
        e1 = __builtin_amdgcn_exp2f((x1 - M.y) * LOG2E);
        float2 sm; sm.x = e0; sm.y = e1;
#pragma unroll
        for (int off = 32; off >= 1; off >>= 1) {
            sm.x += __shfl_xor(sm.x, off);
            sm.y += __shfl_xor(sm.y, off);
        }
        if (lane == 0) red2[8 + wid] = sm;
    }
    __syncthreads();

    if (tid < 512) {
        const int s = tid;
        float2 SS = red2[8];
#pragma unroll
        for (int i = 9; i < 16; ++i) {
            SS.x += red2[i].x;
            SS.y += red2[i].y;
        }
        const float w0 = e0 * __builtin_amdgcn_rcpf(SS.x);
        const float w1 = e1 * __builtin_amdgcn_rcpf(SS.y);
        float2 wpair; wpair.x = w0; wpair.y = w1;
        wp2[s] = wpair;
        attn[row0 * S_ + s]       = w0;
        attn[(row0 + 1) * S_ + s] = w1;
    }
    __syncthreads();

    // ---- Phase 3: context, all 16 waves ----
    const int g  = tid >> 7;          // s-group 0..7 (64 s each)
    const int v4 = tid & 127;
    const float* vb = value + ((size_t)(b * S_) + g * 64) * D_ + v4 * 4;
    float4 a0; a0.x = 0.f; a0.y = 0.f; a0.z = 0.f; a0.w = 0.f;
    float4 a1 = a0;
#pragma unroll 4
    for (int i = 0; i < 64; ++i) {
        float4 vv = *(const float4*)(vb + (size_t)i * D_);
        float2 w = wp2[g * 64 + i];
        a0.x = fmaf(w.x, vv.x, a0.x); a0.y = fmaf(w.x, vv.y, a0.y);
        a0.z = fmaf(w.x, vv.z, a0.z); a0.w = fmaf(w.x, vv.w, a0.w);
        a1.x = fmaf(w.y, vv.x, a1.x); a1.y = fmaf(w.y, vv.y, a1.y);
        a1.z = fmaf(w.y, vv.z, a1.z); a1.w = fmaf(w.y, vv.w, a1.w);
    }
    part[0][g][v4] = a0;
    part[1][g][v4] = a1;
    __syncthreads();
    if (tid < 256) {
        const int t = tid >> 7, v = tid & 127;
        float4 o; o.x = 0.f; o.y = 0.f; o.z = 0.f; o.w = 0.f;
#pragma unroll
        for (int gg = 0; gg < 8; ++gg) {
            float4 p = part[t][gg][v];
            o.x += p.x; o.y += p.y; o.z += p.z; o.w += p.w;
        }
        *(float4*)(ctx + (row0 + t) * D_ + v * 4) = o;
    }
}

extern "C" void kernel_launch(void* const* d_in, const int* in_sizes, int n_in,
                              void* d_out, int out_size, void* d_ws, size_t ws_size,
                              hipStream_t stream) {
    const float* query = (const float*)d_in[0];
    const float* value = (const float*)d_in[1];
    const int*   mask  = (const int*)  d_in[2];
    const float* W1w   = (const float*)d_in[3];
    const float* W1b   = (const float*)d_in[4];
    const float* W2w   = (const float*)d_in[5];
    const float* W2b   = (const float*)d_in[6];
    const float* scale = (const float*)d_in[7];

    float* ctx  = (float*)d_out;
    float* attn = (float*)d_out + (size_t)B_ * T_ * D_;

    float* qproj = (float*)d_ws;                       // QN f32 (1 MB)
    unsigned short* kTb = (unsigned short*)(qproj + (size_t)QN);  // KN fp16 E_k (4 MB)

    mfma_gemm<<<576, 256, 0, stream>>>(query, value, W1w, W2w, W1b, W2b,
                                       qproj, kTb);
    fused_attn<<<256, 1024, 0, stream>>>(qproj, kTb, mask, scale, value,
                                         ctx, attn);
}

// Round 3
// 122.561 us; speedup vs baseline: 1.0683x; 1.0129x over previous
//
#include <hip/hip_runtime.h>
#include <hip/hip_bf16.h>
#include <hip/hip_fp16.h>

// Dims fixed by setup_inputs(): b=8, t=64, s=512, qu=vu=d=512.
#define B_  8
#define T_  64
#define S_  512
#define D_  512

#define QN (512 * 512)      // qproj elements (B*T x D)
#define KN (4096 * 512)     // kT elements (B x D x S)

#define TLOG2E 2.8853900817779268f   // 2*log2(e)
#define LOG2E  1.4426950408889634f

typedef __attribute__((ext_vector_type(8))) short bf16x8;
typedef __attribute__((ext_vector_type(4))) float f32x4;

// RNE f32x2 -> packed bf16x2 via v_cvt_pk_bf16_f32.
__device__ __forceinline__ unsigned int pk2(float a, float b) {
    float2 f; f.x = a; f.y = b;
    __hip_bfloat162 h = __float22bfloat162_rn(f);
    return *(unsigned int*)&h;
}
// RNE f32x2 -> packed fp16x2
__device__ __forceinline__ unsigned int pkh(float a, float b) {
    __half2 h = __floats2half2_rn(a, b);
    return *(unsigned int*)&h;
}
// packed fp16x2 -> two f32
__device__ __forceinline__ float2 up2(unsigned int u) {
    __half2 h = *(__half2*)&u;
    return __half22float2(h);
}

// ---------------------------------------------------------------------------
// bf16 MFMA projection GEMM (R10 576x256 BK=64 dbuf shape — best measured).
// R14: k-branch epilogue stores E_k = exp2(k*2log2e) as FP16 (exp
// factorization e^{2(q+k)} = e^{2q} * e^{2k}) — removed exp2 from the
// consumer's 134M-element loop. Confirmed ~3-4us win.
// R15: +32 blocks (x in [576,608)) emit value as fp16 (vh) so fused phase 3
// reads half the bytes through the per-XCD L2 (32 -> 16 MB/XCD).
//   blocks [0,512):   kTb = exp2((value @ W2)^T * TLOG2E), fp16
//   blocks [512,576): qproj = (query @ W1 + b1 + b2) * TLOG2E, f32
//   blocks [576,608): vh = fp16(value)
// ---------------------------------------------------------------------------
__global__ __launch_bounds__(256) void mfma_gemm(
    const float* __restrict__ query, const float* __restrict__ value,
    const float* __restrict__ W1, const float* __restrict__ W2,
    const float* __restrict__ b1, const float* __restrict__ b2,
    float* __restrict__ qproj, unsigned short* __restrict__ kTb,
    unsigned short* __restrict__ vh)
{
    __shared__ __align__(16) unsigned short Ab[2][64][72];
    __shared__ __align__(16) unsigned short Bs[2][64][72];

    const int x = blockIdx.x;
    const int tid  = threadIdx.x;

    if (x >= 576) {
        // value f32 -> fp16 copy: 32 blocks x 128 rows (4096x512 total).
        const int c = x - 576;
        const float* src = value + (size_t)c * 128 * 512;
        unsigned short* dst = vh + (size_t)c * 128 * 512;
#pragma unroll 4
        for (int i = 0; i < 64; ++i) {
            const int f = i * 256 + tid;              // float4 index in 128*128
            float4 v4 = *(const float4*)(src + (size_t)f * 4);
            uint2 o; o.x = pkh(v4.x, v4.y); o.y = pkh(v4.z, v4.w);
            *(uint2*)(dst + (size_t)f * 4) = o;
        }
        return;
    }

    const float *A, *W;
    int tm, tn;
    bool isq;
    if (x < 512) {
        tm = (x & 7) * 8 + ((x >> 3) & 7);
        tn = x >> 6;
        A = value; W = W2; isq = false;
    } else {
        int r = x - 512;
        tm = r >> 3; tn = r & 7;
        A = query; W = W1; isq = true;
    }

    const int lane = tid & 63;
    const int wid  = tid >> 6;
    const int wm = (wid & 1) * 32, wn = (wid >> 1) * 32;
    const int fm = lane & 15, fq = lane >> 4;

    f32x4 acc00 = {0.f, 0.f, 0.f, 0.f};
    f32x4 acc01 = acc00, acc10 = acc00, acc11 = acc00;

    const int ar = tid >> 2;
    const int kc = (tid & 3) * 16;
    const float* Ag = A + (size_t)(tm * 64 + ar) * 512 + kc;
    const int c0 = (tid & 15) * 4;
    const int kp = (tid >> 4) * 2;
    const float* Wg = W + (size_t)kp * 512 + tn * 64 + c0;

    float4 av0, av1, av2, av3;
    float4 wv0, wv1, wv2, wv3;

#define LOADT(KOFF) do {                                                      \
        av0 = *(const float4*)(Ag + (KOFF));                                  \
        av1 = *(const float4*)(Ag + (KOFF) + 4);                              \
        av2 = *(const float4*)(Ag + (KOFF) + 8);                              \
        av3 = *(const float4*)(Ag + (KOFF) + 12);                             \
        wv0 = *(const float4*)(Wg + (size_t)(KOFF) * 512);                    \
        wv1 = *(const float4*)(Wg + (size_t)(KOFF) * 512 + 512);              \
        wv2 = *(const float4*)(Wg + (size_t)((KOFF) + 32) * 512);             \
        wv3 = *(const float4*)(Wg + (size_t)((KOFF) + 32) * 512 + 512);       \
    } while (0)

#define STAGE(BUF) do {                                                       \
        uint4 p0, p1;                                                         \
        p0.x = pk2(av0.x, av0.y); p0.y = pk2(av0.z, av0.w);                   \
        p0.z = pk2(av1.x, av1.y); p0.w = pk2(av1.z, av1.w);                   \
        p1.x = pk2(av2.x, av2.y); p1.y = pk2(av2.z, av2.w);                   \
        p1.z = pk2(av3.x, av3.y); p1.w = pk2(av3.z, av3.w);                   \
        *(uint4*)&Ab[BUF][ar][kc]     = p0;                                   \
        *(uint4*)&Ab[BUF][ar][kc + 8] = p1;                                   \
        *(unsigned int*)&Bs[BUF][c0 + 0][kp]      = pk2(wv0.x, wv1.x);        \
        *(unsigned int*)&Bs[BUF][c0 + 1][kp]      = pk2(wv0.y, wv1.y);        \
        *(unsigned int*)&Bs[BUF][c0 + 2][kp]      = pk2(wv0.z, wv1.z);        \
        *(unsigned int*)&Bs[BUF][c0 + 3][kp]      = pk2(wv0.w, wv1.w);        \
        *(unsigned int*)&Bs[BUF][c0 + 0][kp + 32] = pk2(wv2.x, wv3.x);        \
        *(unsigned int*)&Bs[BUF][c0 + 1][kp + 32] = pk2(wv2.y, wv3.y);        \
        *(unsigned int*)&Bs[BUF][c0 + 2][kp + 32] = pk2(wv2.z, wv3.z);        \
        *(unsigned int*)&Bs[BUF][c0 + 3][kp + 32] = pk2(wv2.w, wv3.w);        \
    } while (0)

    LOADT(0);
    STAGE(0);
    LOADT(64);
    __syncthreads();

    for (int i = 0; i < 8; ++i) {
        const int cur = i & 1, nxt = cur ^ 1;
        bf16x8 a0, a1, b0, b1v;
#pragma unroll
        for (int kk = 0; kk < 64; kk += 32) {
            a0  = *(const bf16x8*)&Ab[cur][wm + fm][kk + fq * 8];
            a1  = *(const bf16x8*)&Ab[cur][wm + 16 + fm][kk + fq * 8];
            b0  = *(const bf16x8*)&Bs[cur][wn + fm][kk + fq * 8];
            b1v = *(const bf16x8*)&Bs[cur][wn + 16 + fm][kk + fq * 8];
            acc00 = __builtin_amdgcn_mfma_f32_16x16x32_bf16(a0, b0,  acc00, 0, 0, 0);
            acc01 = __builtin_amdgcn_mfma_f32_16x16x32_bf16(a0, b1v, acc01, 0, 0, 0);
            acc10 = __builtin_amdgcn_mfma_f32_16x16x32_bf16(a1, b0,  acc10, 0, 0, 0);
            acc11 = __builtin_amdgcn_mfma_f32_16x16x32_bf16(a1, b1v, acc11, 0, 0, 0);
        }
        if (i < 7) {
            STAGE(nxt);
            const int kn = ((i + 2) & 7) * 64;
            LOADT(kn);
        }
        __syncthreads();
    }
#undef STAGE
#undef LOADT

    // C/D layout (m89-verified): col = lane&15, row = fq*4 + reg.
    const int n0 = tn * 64 + wn + fm;
    const int n1 = n0 + 16;
    const int m0 = tm * 64 + wm + fq * 4;
    if (isq) {
        float bias0 = b1[n0] + b2[n0];
        float bias1 = b1[n1] + b2[n1];
#pragma unroll
        for (int r = 0; r < 4; ++r) {
            qproj[(size_t)(m0 + r) * 512 + n0]      = (acc00[r] + bias0) * TLOG2E;
            qproj[(size_t)(m0 + r) * 512 + n1]      = (acc01[r] + bias1) * TLOG2E;
            qproj[(size_t)(m0 + 16 + r) * 512 + n0] = (acc10[r] + bias0) * TLOG2E;
            qproj[(size_t)(m0 + 16 + r) * 512 + n1] = (acc11[r] + bias1) * TLOG2E;
        }
    } else {
        // kTb[(bb*512 + d)*512 + s] fp16 E_k; acc regs = 4 consecutive s at d.
        const int bb = m0 >> 9;
        const int sl = m0 & 511;
        unsigned short* kb = kTb + (size_t)(bb * 512) * 512;
#define EX2(V) __builtin_amdgcn_exp2f((V) * TLOG2E)
        uint2 o;
        o.x = pkh(EX2(acc00[0]), EX2(acc00[1]));
        o.y = pkh(EX2(acc00[2]), EX2(acc00[3]));
        *(uint2*)(kb + (size_t)n0 * 512 + sl) = o;
        o.x = pkh(EX2(acc10[0]), EX2(acc10[1]));
        o.y = pkh(EX2(acc10[2]), EX2(acc10[3]));
        *(uint2*)(kb + (size_t)n0 * 512 + sl + 16) = o;
        o.x = pkh(EX2(acc01[0]), EX2(acc01[1]));
        o.y = pkh(EX2(acc01[2]), EX2(acc01[3]));
        *(uint2*)(kb + (size_t)n1 * 512 + sl) = o;
        o.x = pkh(EX2(acc11[0]), EX2(acc11[1]));
        o.y = pkh(EX2(acc11[2]), EX2(acc11[3]));
        *(uint2*)(kb + (size_t)n1 * 512 + sl + 16) = o;
#undef EX2
    }
}

// ---------------------------------------------------------------------------
// Fused scores + softmax + context (R12 3-phase structure; R13 split
// regressed). R14: E_k factorization (trans 1.5 -> 1.0 per element).
// R15: phase 3 reads value as fp16 (vh) — per-XCD L2 traffic for value
// halves (32 -> 16 MB/XCD, ~7.4 -> ~3.7 us on the phase-3 critical path).
// ---------------------------------------------------------------------------
__global__ __launch_bounds__(1024) void fused_attn(
    const float* __restrict__ qproj, const unsigned short* __restrict__ kTb,
    const int*   __restrict__ mask,  const float* __restrict__ scale,
    const unsigned short* __restrict__ vh,
    float* __restrict__ ctx, float* __restrict__ attn)
{
    const int blk = blockIdx.x;
    const int b  = blk & 7;
    const int tp = blk >> 3;          // 0..31
    const size_t row0 = (size_t)(b * T_ + tp * 2);

    __shared__ __align__(16) float q0A[512];   // E_q0 = e^{2 q0}
    __shared__ __align__(16) float dA[512];    // delta = e^{2 (q1-q0)}
    __shared__ __align__(16) float cA[512];
    __shared__ __align__(16) float4 pex[4][256];   // (t0s0,t1s0,t0s1,t1s1)
    __shared__ __align__(16) float2 wp2[512];
    __shared__ __align__(16) float4 part[2][8][128];
    __shared__ float2 red2[16];

    const int tid  = threadIdx.x;     // 0..1023
    const int lane = tid & 63;
    const int wid  = tid >> 6;        // 0..15

    // ---- Phase 0: E_q0 / delta / scale into LDS ----
    if (tid < 512) {
        float q0v = qproj[row0 * D_ + tid];          // pre-scaled by 2*log2(e)
        float q1v = qproj[(row0 + 1) * D_ + tid];
        q0A[tid] = __builtin_amdgcn_exp2f(q0v);      // E_q0
        dA[tid]  = __builtin_amdgcn_exp2f(q1v - q0v);
        cA[tid]  = scale[tid];
    }
    __syncthreads();

    // ---- Phase 1: thread (sp, dq), fp16 E_k ----
    const int sp  = tid & 255;        // s-pair
    const int dq  = tid >> 8;         // d-quarter
    const int dlo = dq * 128;
    const unsigned short* kb = kTb + ((size_t)(b * 512 + dlo)) * 512 + sp * 2;

    float p00 = 0.f, p10 = 0.f, p01 = 0.f, p11 = 0.f;

    unsigned int nf0 = *(const unsigned int*)(kb);
    unsigned int nf1 = *(const unsigned int*)(kb + 512);
    unsigned int nf2 = *(const unsigned int*)(kb + 1024);
    unsigned int nf3 = *(const unsigned int*)(kb + 1536);

#define SC2(KU, EQ, DV, CV) do {                                              \
        float2 ek = up2(KU);                                                  \
        float e0 = (EQ) * ek.x;                                               \
        float ra = __builtin_amdgcn_rcpf(e0 + 1.0f);                          \
        float rb = __builtin_amdgcn_rcpf(fmaf(e0, (DV), 1.0f));               \
        p00 = fmaf((CV), ra, p00); p10 = fmaf((CV), rb, p10);                 \
        float e1 = (EQ) * ek.y;                                               \
        float rc = __builtin_amdgcn_rcpf(e1 + 1.0f);                          \
        float rd = __builtin_amdgcn_rcpf(fmaf(e1, (DV), 1.0f));               \
        p01 = fmaf((CV), rc, p01); p11 = fmaf((CV), rd, p11);                 \
    } while (0)

    for (int g = 0; g < 32; ++g) {
        unsigned int kf0 = nf0, kf1 = nf1, kf2 = nf2, kf3 = nf3;
        const unsigned short* nb = kb + (size_t)(((g + 1) & 31) * 4) * 512;
        nf0 = *(const unsigned int*)(nb);
        nf1 = *(const unsigned int*)(nb + 512);
        nf2 = *(const unsigned int*)(nb + 1024);
        nf3 = *(const unsigned int*)(nb + 1536);
        const int d0 = dlo + g * 4;
        float4 q4 = *(const float4*)&q0A[d0];
        float4 dl = *(const float4*)&dA[d0];
        float4 c4 = *(const float4*)&cA[d0];
        SC2(kf0, q4.x, dl.x, c4.x);
        SC2(kf1, q4.y, dl.y, c4.y);
        SC2(kf2, q4.z, dl.z, c4.z);
        SC2(kf3, q4.w, dl.w, c4.w);
    }
#undef SC2

    {
        float4 pq; pq.x = p00; pq.y = p10; pq.z = p01; pq.w = p11;
        pex[dq][sp] = pq;
    }
    __syncthreads();

    // ---- Phase 2: softmax over 512 s (waves 0-7), barriers block-wide ----
    float x0 = 0.f, x1 = 0.f;
    if (tid < 512) {
        const int s = tid;
        const int s2 = s >> 1;
        const bool odd = (s & 1) != 0;
        float4 r0 = pex[0][s2], r1 = pex[1][s2];
        float4 r2 = pex[2][s2], r3 = pex[3][s2];
        float pt0 = odd ? ((r0.z + r1.z) + (r2.z + r3.z))
                        : ((r0.x + r1.x) + (r2.x + r3.x));
        float pt1 = odd ? ((r0.w + r1.w) + (r2.w + r3.w))
                        : ((r0.y + r1.y) + (r2.y + r3.y));
        const int m = mask[b * S_ + s];
        x0 = m ? (-2.0f * pt0) : -1e9f;
        x1 = m ? (-2.0f * pt1) : -1e9f;
        float2 mx; mx.x = x0; mx.y = x1;
#pragma unroll
        for (int off = 32; off >= 1; off >>= 1) {
            mx.x = fmaxf(mx.x, __shfl_xor(mx.x, off));
            mx.y = fmaxf(mx.y, __shfl_xor(mx.y, off));
        }
        if (lane == 0) red2[wid] = mx;
    }
    __syncthreads();

    float e0 = 0.f, e1 = 0.f;
    if (tid < 512) {
        float2 M = red2[0];
#pragma unroll
        for (int i = 1; i < 8; ++i) {
            M.x = fmaxf(M.x, red2[i].x);
            M.y = fmaxf(M.y, red2[i].y);
        }
        e0 = __builtin_amdgcn_exp2f((x0 - M.x) * LOG2E);
        e1 = __builtin_amdgcn_exp2f((x1 - M.y) * LOG2E);
        float2 sm; sm.x = e0; sm.y = e1;
#pragma unroll
        for (int off = 32; off >= 1; off >>= 1) {
            sm.x += __shfl_xor(sm.x, off);
            sm.y += __shfl_xor(sm.y, off);
        }
        if (lane == 0) red2[8 + wid] = sm;
    }
    __syncthreads();

    if (tid < 512) {
        const int s = tid;
        float2 SS = red2[8];
#pragma unroll
        for (int i = 9; i < 16; ++i) {
            SS.x += red2[i].x;
            SS.y += red2[i].y;
        }
        const float w0 = e0 * __builtin_amdgcn_rcpf(SS.x);
        const float w1 = e1 * __builtin_amdgcn_rcpf(SS.y);
        float2 wpair; wpair.x = w0; wpair.y = w1;
        wp2[s] = wpair;
        attn[row0 * S_ + s]       = w0;
        attn[(row0 + 1) * S_ + s] = w1;
    }
    __syncthreads();

    // ---- Phase 3: context, all 16 waves, fp16 value ----
    const int g  = tid >> 7;          // s-group 0..7 (64 s each)
    const int v4 = tid & 127;
    const unsigned short* vb = vh + ((size_t)(b * S_) + g * 64) * D_ + v4 * 4;
    float4 a0; a0.x = 0.f; a0.y = 0.f; a0.z = 0.f; a0.w = 0.f;
    float4 a1 = a0;
#pragma unroll 4
    for (int i = 0; i < 64; ++i) {
        uint2 u = *(const uint2*)(vb + (size_t)i * D_);
        float2 lo = up2(u.x), hi = up2(u.y);
        float2 w = wp2[g * 64 + i];
        a0.x = fmaf(w.x, lo.x, a0.x); a0.y = fmaf(w.x, lo.y, a0.y);
        a0.z = fmaf(w.x, hi.x, a0.z); a0.w = fmaf(w.x, hi.y, a0.w);
        a1.x = fmaf(w.y, lo.x, a1.x); a1.y = fmaf(w.y, lo.y, a1.y);
        a1.z = fmaf(w.y, hi.x, a1.z); a1.w = fmaf(w.y, hi.y, a1.w);
    }
    part[0][g][v4] = a0;
    part[1][g][v4] = a1;
    __syncthreads();
    if (tid < 256) {
        const int t = tid >> 7, v = tid & 127;
        float4 o; o.x = 0.f; o.y = 0.f; o.z = 0.f; o.w = 0.f;
#pragma unroll
        for (int gg = 0; gg < 8; ++gg) {
            float4 p = part[t][gg][v];
            o.x += p.x; o.y += p.y; o.z += p.z; o.w += p.w;
        }
        *(float4*)(ctx + (row0 + t) * D_ + v * 4) = o;
    }
}

extern "C" void kernel_launch(void* const* d_in, const int* in_sizes, int n_in,
                              void* d_out, int out_size, void* d_ws, size_t ws_size,
                              hipStream_t stream) {
    const float* query = (const float*)d_in[0];
    const float* value = (const float*)d_in[1];
    const int*   mask  = (const int*)  d_in[2];
    const float* W1w   = (const float*)d_in[3];
    const float* W1b   = (const float*)d_in[4];
    const float* W2w   = (const float*)d_in[5];
    const float* W2b   = (const float*)d_in[6];
    const float* scale = (const float*)d_in[7];

    float* ctx  = (float*)d_out;
    float* attn = (float*)d_out + (size_t)B_ * T_ * D_;

    float* qproj = (float*)d_ws;                       // QN f32 (1 MB)
    unsigned short* kTb = (unsigned short*)(qproj + (size_t)QN);  // KN fp16 E_k (4 MB)
    unsigned short* vh  = kTb + (size_t)KN;            // KN fp16 value (4 MB)

    mfma_gemm<<<608, 256, 0, stream>>>(query, value, W1w, W2w, W1b, W2b,
                                       qproj, kTb, vh);
    fused_attn<<<256, 1024, 0, stream>>>(qproj, kTb, mask, scale, vh,
                                         ctx, attn);
}